// Round 1
// baseline (3015.801 us; speedup 1.0000x reference)
//
#include <hip/hip_runtime.h>

namespace {
constexpr int C_  = 192;   // channels
constexpr int T_  = 64;    // tokens per window (8x8)
constexpr int NH_ = 6;
constexpr int HD_ = 32;
constexpr int SH_ = 4;     // shift
constexpr int RES = 256;   // H = W
constexpr float SCALE_ = 0.17677669529663687f;  // 1/sqrt(32)
}

// One block per window. 4096 windows, 512 threads (8 waves).
// LDS ~151 KB -> 1 block/CU, 2 waves/SIMD.
__global__ __launch_bounds__(512, 2)
void win_attn_fused(const float* __restrict__ x,
                    const float* __restrict__ qkv_w,
                    const float* __restrict__ qkv_b,
                    const float* __restrict__ proj_w,
                    const float* __restrict__ proj_b,
                    float* __restrict__ out) {
  __shared__ float xs[C_][T_];        // 48 KB, x window, k-major [ch][tok]
  __shared__ float os[C_][T_];        // 48 KB, attention output, k-major [ch][tok]
  __shared__ float wbuf[3072];        // 12 KB, weight chunk stage
  __shared__ float qs[HD_][T_];       // 8 KB, q^T (pre-scaled)
  __shared__ float ks[HD_][T_];       // 8 KB, k^T
  __shared__ float vs[T_][HD_ + 1];   // 8.25 KB, v (padded +1 vs bank conflicts)
  __shared__ float st[T_][T_];        // 16 KB, scores transposed st[j][i]
  __shared__ float part[8][T_];       // 2 KB, softmax partials
  __shared__ float rowmax[T_];
  __shared__ float rowinv[T_];

  const int tid = threadIdx.x;
  const int wid = blockIdx.x;
  const int b  = wid >> 10;        // 32*32 windows per image
  const int wh = (wid >> 5) & 31;
  const int ww = wid & 31;

  // ---- Stage 1: gather rolled (-SHIFT) window into xs[ch][tok].
  // 3072 float4 loads total; +SHIFT makes every (ch,row) two ALIGNED float4,
  // wrap at ww=31 lands exactly on a float4 boundary.
#pragma unroll
  for (int t = 0; t < 6; ++t) {
    const int f = tid + t * 512;
    const int ch = f >> 4;
    const int rem = f & 15;
    const int r = rem >> 1;
    const int half = rem & 1;
    const int h = (wh * 8 + r + SH_) & (RES - 1);
    const int w4 = (ww * 8 + half * 4 + SH_) & (RES - 1);
    const float4 v = *reinterpret_cast<const float4*>(
        x + (((size_t)b * C_ + ch) * RES + h) * RES + w4);
    *reinterpret_cast<float4*>(&xs[ch][r * 8 + half * 4]) = v;
  }
  __syncthreads();

  const int ti = tid & 15;   // token group (4 tokens each)
  const int tg = tid >> 4;   // 0..31
  const int i0 = ti * 4;

  for (int hd = 0; hd < NH_; ++hd) {
    // ---- QKV GEMM for this head: 64x96 (cols = [q:32 | k:32 | v:32]).
    // Thread tile: 4 tokens x 3 cols.
    const int j0 = tg * 3;
    float acc[4][3] = {{0.f,0.f,0.f},{0.f,0.f,0.f},{0.f,0.f,0.f},{0.f,0.f,0.f}};
    for (int kc = 0; kc < C_; kc += 32) {
      __syncthreads();  // protect wbuf reuse
#pragma unroll
      for (int t = 0; t < 6; ++t) {
        const int idx = tid + t * 512;
        const int kk = idx / 96;
        const int j  = idx - kk * 96;
        const int col = (j < 32) ? (hd * 32 + j)
                      : (j < 64) ? (192 + hd * 32 + (j - 32))
                                 : (384 + hd * 32 + (j - 64));
        wbuf[idx] = qkv_w[(size_t)(kc + kk) * 576 + col];
      }
      __syncthreads();
#pragma unroll
      for (int kk = 0; kk < 32; ++kk) {
        const float4 xv = *reinterpret_cast<const float4*>(&xs[kc + kk][i0]);
        const float w0 = wbuf[kk * 96 + j0 + 0];
        const float w1 = wbuf[kk * 96 + j0 + 1];
        const float w2 = wbuf[kk * 96 + j0 + 2];
        acc[0][0] = fmaf(xv.x, w0, acc[0][0]);
        acc[1][0] = fmaf(xv.y, w0, acc[1][0]);
        acc[2][0] = fmaf(xv.z, w0, acc[2][0]);
        acc[3][0] = fmaf(xv.w, w0, acc[3][0]);
        acc[0][1] = fmaf(xv.x, w1, acc[0][1]);
        acc[1][1] = fmaf(xv.y, w1, acc[1][1]);
        acc[2][1] = fmaf(xv.z, w1, acc[2][1]);
        acc[3][1] = fmaf(xv.w, w1, acc[3][1]);
        acc[0][2] = fmaf(xv.x, w2, acc[0][2]);
        acc[1][2] = fmaf(xv.y, w2, acc[1][2]);
        acc[2][2] = fmaf(xv.z, w2, acc[2][2]);
        acc[3][2] = fmaf(xv.w, w2, acc[3][2]);
      }
    }
    // Scatter to qs/ks/vs with bias (q pre-scaled by 1/sqrt(HD)).
#pragma unroll
    for (int jj = 0; jj < 3; ++jj) {
      const int j = j0 + jj;
      const int col = (j < 32) ? (hd * 32 + j)
                    : (j < 64) ? (192 + hd * 32 + (j - 32))
                               : (384 + hd * 32 + (j - 64));
      const float bias = qkv_b[col];
#pragma unroll
      for (int ii = 0; ii < 4; ++ii) {
        const float val = acc[ii][jj] + bias;
        const int i = i0 + ii;
        if (j < 32)       qs[j][i] = val * SCALE_;
        else if (j < 64)  ks[j - 32][i] = val;
        else              vs[i][j - 64] = val;
      }
    }
    __syncthreads();

    // ---- Scores: st[j][i] = sum_d qs[d][i]*ks[d][j]. Thread: 4 i x 2 j.
    {
      const int jq0 = tg * 2;
      float s0[4] = {0.f,0.f,0.f,0.f}, s1[4] = {0.f,0.f,0.f,0.f};
#pragma unroll
      for (int d = 0; d < HD_; ++d) {
        const float4 qv = *reinterpret_cast<const float4*>(&qs[d][i0]);
        const float k0 = ks[d][jq0];
        const float k1 = ks[d][jq0 + 1];
        s0[0] = fmaf(qv.x, k0, s0[0]);
        s0[1] = fmaf(qv.y, k0, s0[1]);
        s0[2] = fmaf(qv.z, k0, s0[2]);
        s0[3] = fmaf(qv.w, k0, s0[3]);
        s1[0] = fmaf(qv.x, k1, s1[0]);
        s1[1] = fmaf(qv.y, k1, s1[1]);
        s1[2] = fmaf(qv.z, k1, s1[2]);
        s1[3] = fmaf(qv.w, k1, s1[3]);
      }
#pragma unroll
      for (int ii = 0; ii < 4; ++ii) {
        st[jq0 + 0][i0 + ii] = s0[ii];
        st[jq0 + 1][i0 + ii] = s1[ii];
      }
    }
    __syncthreads();

    // ---- Softmax over j for each row i (8 threads per row).
    {
      const int i  = tid & 63;
      const int jg = tid >> 6;  // 0..7
      float m = -3.0e38f;
#pragma unroll
      for (int jj = 0; jj < 8; ++jj) m = fmaxf(m, st[jg * 8 + jj][i]);
      part[jg][i] = m;
      __syncthreads();
      if (tid < 64) {
        float mm = part[0][tid];
#pragma unroll
        for (int p = 1; p < 8; ++p) mm = fmaxf(mm, part[p][tid]);
        rowmax[tid] = mm;
      }
      __syncthreads();
      const float mr = rowmax[i];
      float ssum = 0.f;
#pragma unroll
      for (int jj = 0; jj < 8; ++jj) {
        const int j = jg * 8 + jj;
        const float e = __expf(st[j][i] - mr);
        st[j][i] = e;
        ssum += e;
      }
      part[jg][i] = ssum;
      __syncthreads();
      if (tid < 64) {
        float ss = part[0][tid];
#pragma unroll
        for (int p = 1; p < 8; ++p) ss += part[p][tid];
        rowinv[tid] = 1.0f / ss;
      }
      __syncthreads();
    }

    // ---- O = P @ V (normalization folded into write). Thread: 4 i x 1 n.
    {
      const int n = tg;  // 0..31
      float oa[4] = {0.f,0.f,0.f,0.f};
#pragma unroll
      for (int j = 0; j < T_; ++j) {
        const float4 sv = *reinterpret_cast<const float4*>(&st[j][i0]);
        const float vv = vs[j][n];
        oa[0] = fmaf(sv.x, vv, oa[0]);
        oa[1] = fmaf(sv.y, vv, oa[1]);
        oa[2] = fmaf(sv.z, vv, oa[2]);
        oa[3] = fmaf(sv.w, vv, oa[3]);
      }
#pragma unroll
      for (int ii = 0; ii < 4; ++ii)
        os[hd * HD_ + n][i0 + ii] = oa[ii] * rowinv[i0 + ii];
    }
    __syncthreads();
  }

  // ---- Proj GEMM: 64x192, thread tile 4 tokens x 6 cols, K chunked by 16.
  {
    const int c0 = tg * 6;
    float pa[4][6] = {{0.f,0.f,0.f,0.f,0.f,0.f},{0.f,0.f,0.f,0.f,0.f,0.f},
                      {0.f,0.f,0.f,0.f,0.f,0.f},{0.f,0.f,0.f,0.f,0.f,0.f}};
    for (int kc = 0; kc < C_; kc += 16) {
      __syncthreads();
#pragma unroll
      for (int t = 0; t < 6; ++t) {
        const int idx = tid + t * 512;
        const int kk = idx / 192;
        const int c  = idx - kk * 192;
        wbuf[idx] = proj_w[(size_t)(kc + kk) * 192 + c];
      }
      __syncthreads();
#pragma unroll
      for (int kk = 0; kk < 16; ++kk) {
        const float4 ov = *reinterpret_cast<const float4*>(&os[kc + kk][i0]);
#pragma unroll
        for (int cc = 0; cc < 6; ++cc) {
          const float wv = wbuf[kk * 192 + c0 + cc];
          pa[0][cc] = fmaf(ov.x, wv, pa[0][cc]);
          pa[1][cc] = fmaf(ov.y, wv, pa[1][cc]);
          pa[2][cc] = fmaf(ov.z, wv, pa[2][cc]);
          pa[3][cc] = fmaf(ov.w, wv, pa[3][cc]);
        }
      }
    }
    // ---- Scatter-store with inverse roll (+SHIFT). The 4 tokens of this
    // thread are one aligned float4 in w (wrap lands on float4 boundary).
    const int r  = i0 >> 3;
    const int cw = i0 & 7;    // 0 or 4
    const int hg = (wh * 8 + r + SH_) & (RES - 1);
    const int wg = (ww * 8 + cw + SH_) & (RES - 1);
#pragma unroll
    for (int cc = 0; cc < 6; ++cc) {
      const float bias = proj_b[c0 + cc];
      float4 v;
      v.x = pa[0][cc] + bias;
      v.y = pa[1][cc] + bias;
      v.z = pa[2][cc] + bias;
      v.w = pa[3][cc] + bias;
      *reinterpret_cast<float4*>(
          out + (((size_t)b * C_ + (c0 + cc)) * RES + hg) * RES + wg) = v;
    }
  }
}

extern "C" void kernel_launch(void* const* d_in, const int* in_sizes, int n_in,
                              void* d_out, int out_size, void* d_ws, size_t ws_size,
                              hipStream_t stream) {
  (void)in_sizes; (void)n_in; (void)d_ws; (void)ws_size; (void)out_size;
  const float* x      = (const float*)d_in[0];
  const float* qkv_w  = (const float*)d_in[1];
  const float* qkv_b  = (const float*)d_in[2];
  const float* proj_w = (const float*)d_in[3];
  const float* proj_b = (const float*)d_in[4];
  float* out = (float*)d_out;
  win_attn_fused<<<4096, 512, 0, stream>>>(x, qkv_w, qkv_b, proj_w, proj_b, out);
}

// Round 2
// 966.904 us; speedup vs baseline: 3.1190x; 3.1190x over previous
//
#include <hip/hip_runtime.h>

typedef _Float16 half8 __attribute__((ext_vector_type(8)));
typedef _Float16 half2v __attribute__((ext_vector_type(2)));
typedef float floatx4 __attribute__((ext_vector_type(4)));

namespace {
constexpr int RES = 256;
constexpr float SCALE_ = 0.17677669529663687f;  // 1/sqrt(32)
}

// ---- prep: transpose+convert weights to fp16 in workspace.
// qkv_wt[col][k] (576 x 192), proj_wt[col][k] (192 x 192). ws needs 294912 B.
__global__ void prep_weights(const float* __restrict__ qkv_w,
                             const float* __restrict__ proj_w,
                             _Float16* __restrict__ qkv_wt,
                             _Float16* __restrict__ proj_wt) {
  const int col = blockIdx.x;
  const int k = threadIdx.x;  // 192
  if (col < 576) {
    qkv_wt[col * 192 + k] = (_Float16)qkv_w[(size_t)k * 576 + col];
  } else {
    const int c = col - 576;
    proj_wt[c * 192 + k] = (_Float16)proj_w[(size_t)k * 192 + c];
  }
}

// One block per 8x8 window; 512 threads (8 waves); 76 KB LDS -> 2 blocks/CU.
// MFMA layouts (16x16x32 f16): A[m=lane&15][k=quad*8+j] (8 contiguous halfs),
// B[k=quad*8+j][n=lane&15] (stored n-major so k is contiguous),
// C/D: col=lane&15, row=quad*4+reg.
__global__ __launch_bounds__(512, 4)
void win_attn_mfma(const float* __restrict__ x,
                   const _Float16* __restrict__ qkv_wt,
                   const float* __restrict__ qkv_b,
                   const _Float16* __restrict__ proj_wt,
                   const float* __restrict__ proj_b,
                   float* __restrict__ out) {
  __shared__ _Float16 xs[64][200];  // tokens x channels (A for QKV), 25.6 KB
  __shared__ _Float16 os[64][200];  // tokens x channels (A for proj), 25.6 KB
  __shared__ _Float16 qB[64][40];   // q [tok][d], pre-scaled          5 KB
  __shared__ _Float16 kB[64][40];   // k [tok][d]                      5 KB
  __shared__ _Float16 vT[32][72];   // v transposed [d][tok]           4.6 KB
  __shared__ _Float16 st[64][72];   // scores then P, [q][ktok]        9.2 KB
  __shared__ float part[8][64];
  __shared__ float rowred[64];      // rowmax, then 1/rowsum

  const int wid = blockIdx.x;
  const int b = wid >> 10, wh = (wid >> 5) & 31, ww = wid & 31;
  const int wv = threadIdx.x >> 6;   // wave 0..7
  const int lane = threadIdx.x & 63;
  const int ln = lane & 15;
  const int quad = lane >> 4;

  // ---- Gather rolled (-4,-4) window -> xs[tok][ch] fp16.
  // Thread handles a channel PAIR so LDS writes are packed b32; per write
  // instr the 64 lanes span all 32 banks twice (2-way, free).
#pragma unroll
  for (int t = 0; t < 3; ++t) {
    const int f = threadIdx.x + t * 512;
    const int c2 = (f & 31) + 32 * (f >> 9);   // channel pair 0..95
    const int tg = (f >> 5) & 15;              // token group (4 tokens)
    const int r = tg >> 1;
    const int cw = (tg & 1) * 4;
    const int h = (wh * 8 + r + 4) & (RES - 1);
    const int w0 = (ww * 8 + cw + 4) & (RES - 1);
    const size_t base = (((size_t)b * 192 + c2 * 2) * RES + h) * RES + w0;
    const float4 va = *reinterpret_cast<const float4*>(x + base);
    const float4 vb = *reinterpret_cast<const float4*>(x + base + (size_t)RES * RES);
    const int tok = tg * 4;
    half2v p;
    p[0] = (_Float16)va.x; p[1] = (_Float16)vb.x;
    *(half2v*)&xs[tok + 0][c2 * 2] = p;
    p[0] = (_Float16)va.y; p[1] = (_Float16)vb.y;
    *(half2v*)&xs[tok + 1][c2 * 2] = p;
    p[0] = (_Float16)va.z; p[1] = (_Float16)vb.z;
    *(half2v*)&xs[tok + 2][c2 * 2] = p;
    p[0] = (_Float16)va.w; p[1] = (_Float16)vb.w;
    *(half2v*)&xs[tok + 3][c2 * 2] = p;
  }
  __syncthreads();

  for (int hd = 0; hd < 6; ++hd) {
    // ---- QKV for this head: 64 x 96 output = 4 mtiles x 6 ntiles.
    // wave -> mt = wv>>1, ntiles (wv&1)*3 + {0,1,2}. A cached in regs.
    {
      const int mt = wv >> 1;
      half8 af[6];
#pragma unroll
      for (int k = 0; k < 6; ++k)
        af[k] = *(const half8*)&xs[mt * 16 + ln][k * 32 + quad * 8];
#pragma unroll
      for (int i = 0; i < 3; ++i) {
        const int nt = (wv & 1) * 3 + i;
        const int sec = nt >> 1;  // 0=q 1=k 2=v
        const int colb = sec * 192 + hd * 32 + (nt & 1) * 16;
        const _Float16* bp = qkv_wt + (size_t)(colb + ln) * 192 + quad * 8;
        floatx4 acc = {0.f, 0.f, 0.f, 0.f};
#pragma unroll
        for (int k = 0; k < 6; ++k) {
          const half8 bf = *(const half8*)(bp + k * 32);
          acc = __builtin_amdgcn_mfma_f32_16x16x32_f16(af[k], bf, acc, 0, 0, 0);
        }
        const float bias = qkv_b[colb + ln];
        const int tok0 = mt * 16 + quad * 4;
        const int d = (nt & 1) * 16 + ln;
        if (sec == 0) {
#pragma unroll
          for (int j = 0; j < 4; ++j)
            qB[tok0 + j][d] = (_Float16)((acc[j] + bias) * SCALE_);
        } else if (sec == 1) {
#pragma unroll
          for (int j = 0; j < 4; ++j)
            kB[tok0 + j][d] = (_Float16)(acc[j] + bias);
        } else {
#pragma unroll
          for (int j = 0; j < 4; ++j)
            vT[d][tok0 + j] = (_Float16)(acc[j] + bias);
        }
      }
    }
    __syncthreads();

    // ---- Scores: 16 tiles (4x4), K=32 -> 1 MFMA each; 2 tiles per wave.
#pragma unroll
    for (int i = 0; i < 2; ++i) {
      const int t = wv * 2 + i;
      const int smt = t >> 2, snt = t & 3;
      const half8 aq = *(const half8*)&qB[smt * 16 + ln][quad * 8];
      const half8 bk = *(const half8*)&kB[snt * 16 + ln][quad * 8];
      floatx4 acc = {0.f, 0.f, 0.f, 0.f};
      acc = __builtin_amdgcn_mfma_f32_16x16x32_f16(aq, bk, acc, 0, 0, 0);
      const int r0 = smt * 16 + quad * 4;
#pragma unroll
      for (int j = 0; j < 4; ++j)
        st[r0 + j][snt * 16 + ln] = (_Float16)acc[j];
    }
    __syncthreads();

    // ---- Softmax over ktok per row; P (already * 1/sum later via rowred).
    {
      const int i = lane;      // row
      const int jg = wv;       // 8-col slice
      const half8 hv = *(const half8*)&st[i][jg * 8];
      float m = -3.0e38f;
#pragma unroll
      for (int j = 0; j < 8; ++j) m = fmaxf(m, (float)hv[j]);
      part[jg][i] = m;
      __syncthreads();
      if (threadIdx.x < 64) {
        float mm = part[0][threadIdx.x];
#pragma unroll
        for (int p = 1; p < 8; ++p) mm = fmaxf(mm, part[p][threadIdx.x]);
        rowred[threadIdx.x] = mm;
      }
      __syncthreads();
      const float mr = rowred[i];
      float s = 0.f;
      half8 ev;
#pragma unroll
      for (int j = 0; j < 8; ++j) {
        const float e = __expf((float)hv[j] - mr);
        s += e;
        ev[j] = (_Float16)e;
      }
      *(half8*)&st[i][jg * 8] = ev;
      part[jg][i] = s;
      __syncthreads();
      if (threadIdx.x < 64) {
        float ss = part[0][threadIdx.x];
#pragma unroll
        for (int p = 1; p < 8; ++p) ss += part[p][threadIdx.x];
        rowred[threadIdx.x] = 1.0f / ss;
      }
      __syncthreads();
    }

    // ---- O = P @ V: 8 tiles (4mt x 2nt), K=64 -> 2 MFMAs; 1 tile per wave.
    {
      const int pmt = wv >> 1, pnt = wv & 1;
      floatx4 acc = {0.f, 0.f, 0.f, 0.f};
#pragma unroll
      for (int ks = 0; ks < 2; ++ks) {
        const half8 ap = *(const half8*)&st[pmt * 16 + ln][ks * 32 + quad * 8];
        const half8 bv = *(const half8*)&vT[pnt * 16 + ln][ks * 32 + quad * 8];
        acc = __builtin_amdgcn_mfma_f32_16x16x32_f16(ap, bv, acc, 0, 0, 0);
      }
      const int tok0 = pmt * 16 + quad * 4;
      const int d = hd * 32 + pnt * 16 + ln;
#pragma unroll
      for (int j = 0; j < 4; ++j)
        os[tok0 + j][d] = (_Float16)(acc[j] * rowred[tok0 + j]);
    }
    __syncthreads();
  }

  // ---- Proj: 64 x 192 = 4 mtiles x 12 ntiles; wave -> mt=wv>>1, 6 ntiles.
  {
    const int mt = wv >> 1, ng = wv & 1;
    half8 af[6];
#pragma unroll
    for (int k = 0; k < 6; ++k)
      af[k] = *(const half8*)&os[mt * 16 + ln][k * 32 + quad * 8];
#pragma unroll
    for (int i = 0; i < 6; ++i) {
      const int nt = ng * 6 + i;
      const int c = nt * 16 + ln;
      const _Float16* bp = proj_wt + (size_t)c * 192 + quad * 8;
      floatx4 acc = {0.f, 0.f, 0.f, 0.f};
#pragma unroll
      for (int k = 0; k < 6; ++k) {
        const half8 bf = *(const half8*)(bp + k * 32);
        acc = __builtin_amdgcn_mfma_f32_16x16x32_f16(af[k], bf, acc, 0, 0, 0);
      }
      const float bias = proj_b[c];
      const int tok0 = mt * 16 + quad * 4;           // 4 consecutive tokens
      const int r = tok0 >> 3, cw = tok0 & 7;        // same window row
      const int h = (wh * 8 + r + 4) & (RES - 1);
      const int w0 = (ww * 8 + cw + 4) & (RES - 1);  // float4-aligned, no
      float4 vv;                                     // intra-float4 wrap
      vv.x = acc[0] + bias;
      vv.y = acc[1] + bias;
      vv.z = acc[2] + bias;
      vv.w = acc[3] + bias;
      *reinterpret_cast<float4*>(
          out + (((size_t)b * 192 + c) * RES + h) * RES + w0) = vv;
    }
  }
}

extern "C" void kernel_launch(void* const* d_in, const int* in_sizes, int n_in,
                              void* d_out, int out_size, void* d_ws, size_t ws_size,
                              hipStream_t stream) {
  (void)in_sizes; (void)n_in; (void)out_size; (void)ws_size;
  const float* x      = (const float*)d_in[0];
  const float* qkv_w  = (const float*)d_in[1];
  const float* qkv_b  = (const float*)d_in[2];
  const float* proj_w = (const float*)d_in[3];
  const float* proj_b = (const float*)d_in[4];
  float* out = (float*)d_out;

  _Float16* qkv_wt  = (_Float16*)d_ws;              // 576*192 halfs
  _Float16* proj_wt = qkv_wt + 576 * 192;           // 192*192 halfs

  prep_weights<<<768, 192, 0, stream>>>(qkv_w, proj_w, qkv_wt, proj_wt);
  win_attn_mfma<<<4096, 512, 0, stream>>>(x, qkv_wt, qkv_b, proj_wt, proj_b, out);
}